// Round 2
// baseline (265.720 us; speedup 1.0000x reference)
//
#include <hip/hip_runtime.h>

typedef __bf16 bf16;
typedef __bf16 bf16x8 __attribute__((ext_vector_type(8)));
typedef float  f32x4  __attribute__((ext_vector_type(4)));
typedef float  f32x16 __attribute__((ext_vector_type(16)));
typedef int    i32x4  __attribute__((ext_vector_type(4)));
typedef int    i32x16 __attribute__((ext_vector_type(16)));
typedef signed char i8;

#define OC_N   4096
#define IC_K   4096
#define TOKENS 4096
#define KC     256   // outlier K padded to 8x32

// ---------------------------------------------------------------------------
// Fused prep, one block per row r (TOKENS == OC_N == 4096).  UNCHANGED.
// ---------------------------------------------------------------------------
__global__ __launch_bounds__(256) void prep_kernel(
    const float* __restrict__ w, const float* __restrict__ x,
    const float* __restrict__ ow, const int* __restrict__ idx,
    i8* __restrict__ wsgn, i8* __restrict__ xq,
    bf16* __restrict__ xo, bf16* __restrict__ wcorr,
    float* __restrict__ scale_arr, float* __restrict__ sx_arr, int n_out)
{
    __shared__ float red[8];
    const int row = blockIdx.x;
    const int t = threadIdx.x;
    const int lane = t & 63, wv = t >> 6;

    const float4* wr = (const float4*)(w + (size_t)row * IC_K);
    const float4* xr = (const float4*)(x + (size_t)row * IC_K);
    float4 v[4], u[4];
#pragma unroll
    for (int i = 0; i < 4; i++) v[i] = wr[i * 256 + t];
#pragma unroll
    for (int i = 0; i < 4; i++) u[i] = xr[i * 256 + t];

    float xg = 0.f, wg = 0.f, og = 0.f;
    if (t < n_out) {
        const int colg = idx[t];
        xg = x[(size_t)row * IC_K + colg];
        wg = w[(size_t)row * IC_K + colg];
        og = ow[(size_t)row * n_out + t];
    }

    float s = 0.f;
#pragma unroll
    for (int i = 0; i < 4; i++)
        s += v[i].x + v[i].y + v[i].z + v[i].w;
    for (int o = 32; o > 0; o >>= 1) s += __shfl_down(s, o, 64);
    if (lane == 0) red[wv] = s;
    __syncthreads();
    const float mean = (red[0] + red[1] + red[2] + red[3]) * (1.f / IC_K);

    float sa = 0.f;
#pragma unroll
    for (int i = 0; i < 4; i++) {
        sa += fabsf(v[i].x - mean) + fabsf(v[i].y - mean) +
              fabsf(v[i].z - mean) + fabsf(v[i].w - mean);
    }
    for (int o = 32; o > 0; o >>= 1) sa += __shfl_down(sa, o, 64);
    if (lane == 0) red[4 + wv] = sa;
    __syncthreads();
    const float scale = (red[4] + red[5] + red[6] + red[7]) * (1.f / IC_K);

    i8* srow = wsgn + (size_t)row * IC_K;
#pragma unroll
    for (int i = 0; i < 4; i++) {
        float c[4] = { v[i].x - mean, v[i].y - mean, v[i].z - mean, v[i].w - mean };
        char4 q;
        q.x = (i8)((c[0] > 0.f) - (c[0] < 0.f));
        q.y = (i8)((c[1] > 0.f) - (c[1] < 0.f));
        q.z = (i8)((c[2] > 0.f) - (c[2] < 0.f));
        q.w = (i8)((c[3] > 0.f) - (c[3] < 0.f));
        *(char4*)(srow + (size_t)(i * 256 + t) * 4) = q;
    }

    float mx = 0.f;
#pragma unroll
    for (int i = 0; i < 4; i++)
        mx = fmaxf(mx, fmaxf(fmaxf(fabsf(u[i].x), fabsf(u[i].y)),
                             fmaxf(fabsf(u[i].z), fabsf(u[i].w))));
    for (int o = 32; o > 0; o >>= 1) mx = fmaxf(mx, __shfl_down(mx, o, 64));
    if (lane == 0) red[wv] = mx;
    __syncthreads();
    const float maxv = fmaxf(fmaxf(red[0], red[1]), fmaxf(red[2], red[3]));
    const float inv = maxv > 0.f ? 127.f / maxv : 0.f;
    const float sxv = maxv > 0.f ? maxv * (1.f / 127.f) : 1.f;

    i8* xrow = xq + (size_t)row * IC_K;
#pragma unroll
    for (int i = 0; i < 4; i++) {
        char4 q;
        q.x = (i8)(int)rintf(u[i].x * inv);
        q.y = (i8)(int)rintf(u[i].y * inv);
        q.z = (i8)(int)rintf(u[i].z * inv);
        q.w = (i8)(int)rintf(u[i].w * inv);
        *(char4*)(xrow + (size_t)(i * 256 + t) * 4) = q;
    }
    if (t == 0) { scale_arr[row] = scale; sx_arr[row] = sxv; }

    if (t < n_out) {
        xo[(size_t)row * KC + t] = (bf16)xg;
        const float wc_ = wg - mean;
        const float sg = (wc_ > 0.f) ? 1.f : ((wc_ < 0.f) ? -1.f : 0.f);
        wcorr[(size_t)row * KC + t] = (bf16)(og - scale * sg);
    } else if (t < KC) {
        xo[(size_t)row * KC + t] = (bf16)0.f;
        wcorr[(size_t)row * KC + t] = (bf16)0.f;
    }
}

// ---------------------------------------------------------------------------
// GEMM v2: 256x256 tile, 8 waves (2Mx4N, 128x64 each), counted-vmcnt ring.
//
// K pipelined as chunks of 64 i8 (64 B rows) through a 4-slot LDS ring
// (4 x {A,B} x 16 KB = 128 KB).  Per phase:
//   issue 4 global_load_lds (chunk c+3)  ->  s_waitcnt vmcnt(12)  ->
//   raw s_barrier (NO implicit vmcnt(0) drain)  ->  12 ds_read_b128 +
//   16 MFMA under setprio(1)  ->  s_barrier.
// Slot s is overwritten exactly 4 phases after its last read, with two
// barriers in between -> race-free.  vmcnt never drains to 0 in steady
// state (3 chunks = 12 loads in flight ~= HBM latency cover).
// VMCNT(12);BAR: every wave individually drains its own stage(c) loads
// before the barrier, so after it ALL waves' chunk-c data is in LDS.
//
// LDS swizzle (both-sides): quad Q = row*4 + (qk ^ ((row>>1)&3)).  Within a
// ds_read_b128 8-lane group, addresses mod 128 cover all eight 16B slots
// exactly once -> conflict-free; inverse (same) permutation applied to the
// global source of global_load_lds (linear LDS dest, rule #21).
//
// bf16 correction (KC=256) = 8 chunks of K=32 bf16: byte-identical 64 B-row
// geometry, same ring/offsets/schedule, accumulating into facc.
// ---------------------------------------------------------------------------
__device__ __forceinline__ void gload16(const void* g, void* l)
{
    __builtin_amdgcn_global_load_lds(
        (const __attribute__((address_space(1))) void*)g,
        (__attribute__((address_space(3))) void*)l, 16, 0, 0);
}

#define VMCNT(n) asm volatile("s_waitcnt vmcnt(" #n ")" ::: "memory")
#define SCHED0   __builtin_amdgcn_sched_barrier(0)
#define BAR      __builtin_amdgcn_s_barrier()

__global__ __launch_bounds__(512, 2) void gemm_kernel(
    const i8* __restrict__ A, const i8* __restrict__ B,
    const bf16* __restrict__ Axo, const bf16* __restrict__ Bwc,
    const float* __restrict__ sx, const float* __restrict__ scale,
    const float* __restrict__ bias, float* __restrict__ C)
{
    constexpr int K = IC_K, N = OC_N;
    __shared__ __align__(16) i8 ring[4][2][16384];   // 128 KB

    const int tid  = threadIdx.x;
    const int lane = tid & 63;
    const int wave = tid >> 6;
    const int wm = wave >> 2, wn = wave & 3;          // 2 (M) x 4 (N) waves
    const int m32 = lane & 31, kg = lane >> 5;

    // XCD-aware bijective swizzle (256 blocks, 256 % 8 == 0)
    const int bid = blockIdx.x;
    const int swz = (bid & 7) * 32 + (bid >> 3);
    const int bm = swz >> 4, bn = swz & 15;

    // ---- staging map: LDS quad Q = tid (+512) -> (row, swizzled qk) ----
    const int Q0 = tid, Q1 = 512 + tid;
    const int r0 = Q0 >> 2, r1 = Q1 >> 2;             // rows 0..127 / 128..255
    const int q0 = (Q0 & 3) ^ ((r0 >> 1) & 3);
    const int q1 = (Q1 & 3) ^ ((r1 >> 1) & 3);
    const int d0 = Q0 * 16, d1 = Q1 * 16;

    const i8* gA0 = A + (size_t)(bm * 256 + r0) * K + q0 * 16;
    const i8* gA1 = A + (size_t)(bm * 256 + r1) * K + q1 * 16;
    const i8* gB0 = B + (size_t)(bn * 256 + r0) * K + q0 * 16;
    const i8* gB1 = B + (size_t)(bn * 256 + r1) * K + q1 * 16;

    auto stage = [&](int c) {
        i8* bs = &ring[c & 3][0][0];
        const int ko = c * 64;
        gload16(gA0 + ko, bs + d0);
        gload16(gA1 + ko, bs + d1);
        gload16(gB0 + ko, bs + 16384 + d0);
        gload16(gB1 + ko, bs + 16384 + d1);
    };

    // ---- per-lane ds_read byte offsets (shared by i8 and bf16 loops) ----
    int offA[4][2], offB[2][2];
#pragma unroll
    for (int mi = 0; mi < 4; ++mi) {
        const int r = wm * 128 + mi * 32 + m32;
#pragma unroll
        for (int ks = 0; ks < 2; ++ks)
            offA[mi][ks] = r * 64 + ((ks * 2 + kg) ^ ((r >> 1) & 3)) * 16;
    }
#pragma unroll
    for (int ni = 0; ni < 2; ++ni) {
        const int r = wn * 64 + ni * 32 + m32;
#pragma unroll
        for (int ks = 0; ks < 2; ++ks)
            offB[ni][ks] = r * 64 + ((ks * 2 + kg) ^ ((r >> 1) & 3)) * 16;
    }

    i32x16 acc[4][2] = {};

    auto phase_i8 = [&](int c) {
        const i8* sA = &ring[c & 3][0][0];
        const i8* sB = sA + 16384;
        i32x4 af[4][2], bfr[2][2];
#pragma unroll
        for (int mi = 0; mi < 4; ++mi)
#pragma unroll
            for (int ks = 0; ks < 2; ++ks)
                af[mi][ks] = *(const i32x4*)(sA + offA[mi][ks]);
#pragma unroll
        for (int ni = 0; ni < 2; ++ni)
#pragma unroll
            for (int ks = 0; ks < 2; ++ks)
                bfr[ni][ks] = *(const i32x4*)(sB + offB[ni][ks]);
        __builtin_amdgcn_s_setprio(1);
#pragma unroll
        for (int ks = 0; ks < 2; ++ks)
#pragma unroll
            for (int mi = 0; mi < 4; ++mi)
#pragma unroll
                for (int ni = 0; ni < 2; ++ni)
                    acc[mi][ni] = __builtin_amdgcn_mfma_i32_32x32x32_i8(
                        af[mi][ks], bfr[ni][ks], acc[mi][ni], 0, 0, 0);
        __builtin_amdgcn_s_setprio(0);
    };

    // ---- main i8 loop: 64 chunks, ring depth 4, vmcnt(12) steady state ----
    stage(0); stage(1); stage(2);
#pragma unroll 4
    for (int c = 0; c < 60; ++c) {
        stage(c + 3);
        VMCNT(12); BAR; SCHED0;
        phase_i8(c);
        SCHED0; BAR;
    }
    stage(63);
    VMCNT(12); BAR; SCHED0; phase_i8(60); SCHED0; BAR;
    VMCNT(8);  BAR; SCHED0; phase_i8(61); SCHED0; BAR;
    VMCNT(4);  BAR; SCHED0; phase_i8(62); SCHED0; BAR;
    VMCNT(0);  BAR; SCHED0; phase_i8(63); SCHED0; BAR;

    // ---- i32 -> f32 scaling (32x32 C layout: row=(r&3)+8*(r>>2)+4*kg) ----
    const int rbase = bm * 256 + wm * 128 + 4 * kg;
    const int cbase = bn * 256 + wn * 64 + m32;
    float scl2[2], bv2[2];
#pragma unroll
    for (int ni = 0; ni < 2; ++ni) {
        scl2[ni] = scale[cbase + ni * 32];
        bv2[ni]  = bias[cbase + ni * 32];
    }
    f32x16 facc[4][2];
#pragma unroll
    for (int mi = 0; mi < 4; ++mi)
#pragma unroll
        for (int r = 0; r < 16; ++r) {
            const float sxv = sx[rbase + mi * 32 + (r & 3) + 8 * (r >> 2)];
#pragma unroll
            for (int ni = 0; ni < 2; ++ni)
                facc[mi][ni][r] = (float)acc[mi][ni][r] * sxv * scl2[ni];
        }
    // drain sx/scale/bias loads so corr-loop vmcnt counts are exact
    asm volatile("s_waitcnt vmcnt(0)" ::: "memory");

    // ---- bf16 correction: 8 chunks of K=32 over KC=256, same schedule ----
    const i8* cA0 = (const i8*)Axo + (size_t)(bm * 256 + r0) * (KC * 2) + q0 * 16;
    const i8* cA1 = (const i8*)Axo + (size_t)(bm * 256 + r1) * (KC * 2) + q1 * 16;
    const i8* cB0 = (const i8*)Bwc + (size_t)(bn * 256 + r0) * (KC * 2) + q0 * 16;
    const i8* cB1 = (const i8*)Bwc + (size_t)(bn * 256 + r1) * (KC * 2) + q1 * 16;
    auto stagec = [&](int c) {
        i8* bs = &ring[c & 3][0][0];
        const int ko = c * 64;
        gload16(cA0 + ko, bs + d0);
        gload16(cA1 + ko, bs + d1);
        gload16(cB0 + ko, bs + 16384 + d0);
        gload16(cB1 + ko, bs + 16384 + d1);
    };
    auto phase_bf = [&](int c) {
        const i8* sA = &ring[c & 3][0][0];
        const i8* sB = sA + 16384;
        bf16x8 af[4][2], bfr[2][2];
#pragma unroll
        for (int mi = 0; mi < 4; ++mi)
#pragma unroll
            for (int ks = 0; ks < 2; ++ks)
                af[mi][ks] = *(const bf16x8*)(sA + offA[mi][ks]);
#pragma unroll
        for (int ni = 0; ni < 2; ++ni)
#pragma unroll
            for (int ks = 0; ks < 2; ++ks)
                bfr[ni][ks] = *(const bf16x8*)(sB + offB[ni][ks]);
        __builtin_amdgcn_s_setprio(1);
#pragma unroll
        for (int ks = 0; ks < 2; ++ks)
#pragma unroll
            for (int mi = 0; mi < 4; ++mi)
#pragma unroll
                for (int ni = 0; ni < 2; ++ni)
                    facc[mi][ni] = __builtin_amdgcn_mfma_f32_32x32x16_bf16(
                        af[mi][ks], bfr[ni][ks], facc[mi][ni], 0, 0, 0);
        __builtin_amdgcn_s_setprio(0);
    };

    stagec(0); stagec(1); stagec(2);
#pragma unroll
    for (int c = 0; c < 5; ++c) {
        stagec(c + 3);
        VMCNT(12); BAR; SCHED0;
        phase_bf(c);
        SCHED0; BAR;
    }
    VMCNT(8); BAR; SCHED0; phase_bf(5); SCHED0; BAR;
    VMCNT(4); BAR; SCHED0; phase_bf(6); SCHED0; BAR;
    VMCNT(0); BAR; SCHED0; phase_bf(7); SCHED0; BAR;

    // ---- epilogue: + bias, store ----
#pragma unroll
    for (int mi = 0; mi < 4; ++mi)
#pragma unroll
        for (int r = 0; r < 16; ++r) {
            const int row = rbase + mi * 32 + (r & 3) + 8 * (r >> 2);
#pragma unroll
            for (int ni = 0; ni < 2; ++ni)
                C[(size_t)row * N + cbase + ni * 32] = facc[mi][ni][r] + bv2[ni];
        }
}

// ---------------------------------------------------------------------------
extern "C" void kernel_launch(void* const* d_in, const int* in_sizes, int n_in,
                              void* d_out, int out_size, void* d_ws, size_t ws_size,
                              hipStream_t stream)
{
    const float* x    = (const float*)d_in[0];
    const float* w    = (const float*)d_in[1];
    const float* bias = (const float*)d_in[2];
    const float* ow   = (const float*)d_in[3];
    const int*   idx  = (const int*)d_in[4];
    const int    n_out = in_sizes[4];
    float* out = (float*)d_out;

    char* ws = (char*)d_ws;
    i8*    xq    = (i8*)ws;                                   // 16 MB
    i8*    wsgn  = (i8*)(ws + (size_t)16 * 1024 * 1024);      // 16 MB
    bf16*  xo    = (bf16*)(ws + (size_t)32 * 1024 * 1024);    // 2 MB
    bf16*  wcorr = (bf16*)(ws + (size_t)34 * 1024 * 1024);    // 2 MB
    float* sx    = (float*)(ws + (size_t)36 * 1024 * 1024);   // 16 KB
    float* scl   = (float*)(ws + (size_t)36 * 1024 * 1024 + 16 * 1024); // 16 KB

    hipLaunchKernelGGL(prep_kernel, dim3(OC_N), dim3(256), 0, stream,
                       w, x, ow, idx, wsgn, xq, xo, wcorr, scl, sx, n_out);
    hipLaunchKernelGGL(gemm_kernel, dim3(256), dim3(512), 0, stream,
                       xq, wsgn, xo, wcorr, sx, scl, bias, out);
}

// Round 4
// 254.899 us; speedup vs baseline: 1.0425x; 1.0425x over previous
//
#include <hip/hip_runtime.h>

typedef __bf16 bf16;
typedef __bf16 bf16x8 __attribute__((ext_vector_type(8)));
typedef float  f32x4  __attribute__((ext_vector_type(4)));
typedef float  f32x16 __attribute__((ext_vector_type(16)));
typedef int    i32x4  __attribute__((ext_vector_type(4)));
typedef int    i32x16 __attribute__((ext_vector_type(16)));
typedef signed char i8;

#define OC_N   4096
#define IC_K   4096
#define TOKENS 4096
#define KC     256   // outlier K padded to 8x32

// ---------------------------------------------------------------------------
// Fused prep, one block per row r (TOKENS == OC_N == 4096).  UNCHANGED.
// ---------------------------------------------------------------------------
__global__ __launch_bounds__(256) void prep_kernel(
    const float* __restrict__ w, const float* __restrict__ x,
    const float* __restrict__ ow, const int* __restrict__ idx,
    i8* __restrict__ wsgn, i8* __restrict__ xq,
    bf16* __restrict__ xo, bf16* __restrict__ wcorr,
    float* __restrict__ scale_arr, float* __restrict__ sx_arr, int n_out)
{
    __shared__ float red[8];
    const int row = blockIdx.x;
    const int t = threadIdx.x;
    const int lane = t & 63, wv = t >> 6;

    const float4* wr = (const float4*)(w + (size_t)row * IC_K);
    const float4* xr = (const float4*)(x + (size_t)row * IC_K);
    float4 v[4], u[4];
#pragma unroll
    for (int i = 0; i < 4; i++) v[i] = wr[i * 256 + t];
#pragma unroll
    for (int i = 0; i < 4; i++) u[i] = xr[i * 256 + t];

    float xg = 0.f, wg = 0.f, og = 0.f;
    if (t < n_out) {
        const int colg = idx[t];
        xg = x[(size_t)row * IC_K + colg];
        wg = w[(size_t)row * IC_K + colg];
        og = ow[(size_t)row * n_out + t];
    }

    float s = 0.f;
#pragma unroll
    for (int i = 0; i < 4; i++)
        s += v[i].x + v[i].y + v[i].z + v[i].w;
    for (int o = 32; o > 0; o >>= 1) s += __shfl_down(s, o, 64);
    if (lane == 0) red[wv] = s;
    __syncthreads();
    const float mean = (red[0] + red[1] + red[2] + red[3]) * (1.f / IC_K);

    float sa = 0.f;
#pragma unroll
    for (int i = 0; i < 4; i++) {
        sa += fabsf(v[i].x - mean) + fabsf(v[i].y - mean) +
              fabsf(v[i].z - mean) + fabsf(v[i].w - mean);
    }
    for (int o = 32; o > 0; o >>= 1) sa += __shfl_down(sa, o, 64);
    if (lane == 0) red[4 + wv] = sa;
    __syncthreads();
    const float scale = (red[4] + red[5] + red[6] + red[7]) * (1.f / IC_K);

    i8* srow = wsgn + (size_t)row * IC_K;
#pragma unroll
    for (int i = 0; i < 4; i++) {
        float c[4] = { v[i].x - mean, v[i].y - mean, v[i].z - mean, v[i].w - mean };
        char4 q;
        q.x = (i8)((c[0] > 0.f) - (c[0] < 0.f));
        q.y = (i8)((c[1] > 0.f) - (c[1] < 0.f));
        q.z = (i8)((c[2] > 0.f) - (c[2] < 0.f));
        q.w = (i8)((c[3] > 0.f) - (c[3] < 0.f));
        *(char4*)(srow + (size_t)(i * 256 + t) * 4) = q;
    }

    float mx = 0.f;
#pragma unroll
    for (int i = 0; i < 4; i++)
        mx = fmaxf(mx, fmaxf(fmaxf(fabsf(u[i].x), fabsf(u[i].y)),
                             fmaxf(fabsf(u[i].z), fabsf(u[i].w))));
    for (int o = 32; o > 0; o >>= 1) mx = fmaxf(mx, __shfl_down(mx, o, 64));
    if (lane == 0) red[wv] = mx;
    __syncthreads();
    const float maxv = fmaxf(fmaxf(red[0], red[1]), fmaxf(red[2], red[3]));
    const float inv = maxv > 0.f ? 127.f / maxv : 0.f;
    const float sxv = maxv > 0.f ? maxv * (1.f / 127.f) : 1.f;

    i8* xrow = xq + (size_t)row * IC_K;
#pragma unroll
    for (int i = 0; i < 4; i++) {
        char4 q;
        q.x = (i8)(int)rintf(u[i].x * inv);
        q.y = (i8)(int)rintf(u[i].y * inv);
        q.z = (i8)(int)rintf(u[i].z * inv);
        q.w = (i8)(int)rintf(u[i].w * inv);
        *(char4*)(xrow + (size_t)(i * 256 + t) * 4) = q;
    }
    if (t == 0) { scale_arr[row] = scale; sx_arr[row] = sxv; }

    if (t < n_out) {
        xo[(size_t)row * KC + t] = (bf16)xg;
        const float wc_ = wg - mean;
        const float sg = (wc_ > 0.f) ? 1.f : ((wc_ < 0.f) ? -1.f : 0.f);
        wcorr[(size_t)row * KC + t] = (bf16)(og - scale * sg);
    } else if (t < KC) {
        xo[(size_t)row * KC + t] = (bf16)0.f;
        wcorr[(size_t)row * KC + t] = (bf16)0.f;
    }
}

// ---------------------------------------------------------------------------
// GEMM v3: 256x256 tile, 8 waves (2Mx4N), counted-vmcnt ring.
// R2 diagnosis: staging-supply-bound (512 MB staged / 123 us = 4.2 TB/s;
// FETCH 112 MB ~= modeled L2-miss traffic of the 2x16 per-XCD tiling).
// Changes v2 -> v3:
//  (1) XCD tiling 2x16 -> 4x8 rectangles: per-XCD L2-miss traffic per phase
//      (bm_cnt+bn_cnt)*16KB = 288 -> 192 KB (-33%).  Predicted FETCH ~75MB.
//  (2) Ring depth 4 -> 5 (160 KB LDS, full pool): in-flight loads 16->20,
//      steady-state wait vmcnt(16).  Slot c%5; main loop unroll 5 (60=12*5).
// Race audit (depth 5): slot s=c%5 is overwritten by stage(c) issued in
// iteration c-4, which is after the trailing barrier of iteration c-5 where
// slot s was last read -> WAR safe.  VMCNT(16);BAR still guarantees all
// waves' chunk-c loads are in LDS before any wave reads them -> RAW safe.
// Bank conflicts (7.1M = +4cy/ds_read): read-vs-concurrent-gload-LDS-write
// port collisions (read-side swizzle verified conflict-free: even lanes
// cover banks 0-15, odd lanes 16-31, each exactly once) — not addressable
// by swizzle, deliberately not targeted this round.
// ---------------------------------------------------------------------------
__device__ __forceinline__ void gload16(const void* g, void* l)
{
    __builtin_amdgcn_global_load_lds(
        (const __attribute__((address_space(1))) void*)g,
        (__attribute__((address_space(3))) void*)l, 16, 0, 0);
}

#define VMCNT(n) asm volatile("s_waitcnt vmcnt(" #n ")" ::: "memory")
#define SCHED0   __builtin_amdgcn_sched_barrier(0)
#define BAR      __builtin_amdgcn_s_barrier()

__global__ __launch_bounds__(512, 2) void gemm_kernel(
    const i8* __restrict__ A, const i8* __restrict__ B,
    const bf16* __restrict__ Axo, const bf16* __restrict__ Bwc,
    const float* __restrict__ sx, const float* __restrict__ scale,
    const float* __restrict__ bias, float* __restrict__ C)
{
    constexpr int K = IC_K, N = OC_N;
    __shared__ __align__(16) i8 ring[5][2][16384];   // 160 KB (full pool)

    const int tid  = threadIdx.x;
    const int lane = tid & 63;
    const int wave = tid >> 6;
    const int wm = wave >> 2, wn = wave & 3;          // 2 (M) x 4 (N) waves
    const int m32 = lane & 31, kg = lane >> 5;

    // XCD-aware 4x8 rectangle per XCD (bijective; 256 blocks, 8 XCDs)
    const int bid = blockIdx.x;
    const int xcd = bid & 7, tix = bid >> 3;          // 32 tiles per XCD
    const int bm = (xcd >> 1) * 4 + (tix & 3);        // 16 values
    const int bn = (xcd & 1) * 8 + (tix >> 2);        // 16 values

    // ---- staging map: LDS quad Q = tid (+512) -> (row, swizzled qk) ----
    const int Q0 = tid, Q1 = 512 + tid;
    const int r0 = Q0 >> 2, r1 = Q1 >> 2;             // rows 0..127 / 128..255
    const int q0 = (Q0 & 3) ^ ((r0 >> 1) & 3);
    const int q1 = (Q1 & 3) ^ ((r1 >> 1) & 3);
    const int d0 = Q0 * 16, d1 = Q1 * 16;

    const i8* gA0 = A + (size_t)(bm * 256 + r0) * K + q0 * 16;
    const i8* gA1 = A + (size_t)(bm * 256 + r1) * K + q1 * 16;
    const i8* gB0 = B + (size_t)(bn * 256 + r0) * K + q0 * 16;
    const i8* gB1 = B + (size_t)(bn * 256 + r1) * K + q1 * 16;

    auto stage = [&](int c) {
        i8* bs = &ring[c % 5][0][0];
        const int ko = c * 64;
        gload16(gA0 + ko, bs + d0);
        gload16(gA1 + ko, bs + d1);
        gload16(gB0 + ko, bs + 16384 + d0);
        gload16(gB1 + ko, bs + 16384 + d1);
    };

    // ---- per-lane ds_read byte offsets (shared by i8 and bf16 loops) ----
    int offA[4][2], offB[2][2];
#pragma unroll
    for (int mi = 0; mi < 4; ++mi) {
        const int r = wm * 128 + mi * 32 + m32;
#pragma unroll
        for (int ks = 0; ks < 2; ++ks)
            offA[mi][ks] = r * 64 + ((ks * 2 + kg) ^ ((r >> 1) & 3)) * 16;
    }
#pragma unroll
    for (int ni = 0; ni < 2; ++ni) {
        const int r = wn * 64 + ni * 32 + m32;
#pragma unroll
        for (int ks = 0; ks < 2; ++ks)
            offB[ni][ks] = r * 64 + ((ks * 2 + kg) ^ ((r >> 1) & 3)) * 16;
    }

    i32x16 acc[4][2] = {};

    auto phase_i8 = [&](int c) {
        const i8* sA = &ring[c % 5][0][0];
        const i8* sB = sA + 16384;
        i32x4 af[4][2], bfr[2][2];
#pragma unroll
        for (int mi = 0; mi < 4; ++mi)
#pragma unroll
            for (int ks = 0; ks < 2; ++ks)
                af[mi][ks] = *(const i32x4*)(sA + offA[mi][ks]);
#pragma unroll
        for (int ni = 0; ni < 2; ++ni)
#pragma unroll
            for (int ks = 0; ks < 2; ++ks)
                bfr[ni][ks] = *(const i32x4*)(sB + offB[ni][ks]);
        __builtin_amdgcn_s_setprio(1);
#pragma unroll
        for (int ks = 0; ks < 2; ++ks)
#pragma unroll
            for (int mi = 0; mi < 4; ++mi)
#pragma unroll
                for (int ni = 0; ni < 2; ++ni)
                    acc[mi][ni] = __builtin_amdgcn_mfma_i32_32x32x32_i8(
                        af[mi][ks], bfr[ni][ks], acc[mi][ni], 0, 0, 0);
        __builtin_amdgcn_s_setprio(0);
    };

    // ---- main i8 loop: 64 chunks, ring depth 5, vmcnt(16) steady state ----
    stage(0); stage(1); stage(2); stage(3);
#pragma unroll 5
    for (int c = 0; c < 60; ++c) {
        stage(c + 4);
        VMCNT(16); BAR; SCHED0;
        phase_i8(c);
        SCHED0; BAR;
    }
    VMCNT(12); BAR; SCHED0; phase_i8(60); SCHED0; BAR;
    VMCNT(8);  BAR; SCHED0; phase_i8(61); SCHED0; BAR;
    VMCNT(4);  BAR; SCHED0; phase_i8(62); SCHED0; BAR;
    VMCNT(0);  BAR; SCHED0; phase_i8(63); SCHED0; BAR;

    // ---- i32 -> f32 scaling (32x32 C layout: row=(r&3)+8*(r>>2)+4*kg) ----
    const int rbase = bm * 256 + wm * 128 + 4 * kg;
    const int cbase = bn * 256 + wn * 64 + m32;
    float scl2[2], bv2[2];
#pragma unroll
    for (int ni = 0; ni < 2; ++ni) {
        scl2[ni] = scale[cbase + ni * 32];
        bv2[ni]  = bias[cbase + ni * 32];
    }
    f32x16 facc[4][2];
#pragma unroll
    for (int mi = 0; mi < 4; ++mi)
#pragma unroll
        for (int r = 0; r < 16; ++r) {
            const float sxv = sx[rbase + mi * 32 + (r & 3) + 8 * (r >> 2)];
#pragma unroll
            for (int ni = 0; ni < 2; ++ni)
                facc[mi][ni][r] = (float)acc[mi][ni][r] * sxv * scl2[ni];
        }
    // drain sx/scale/bias loads so corr-loop vmcnt counts are exact
    asm volatile("s_waitcnt vmcnt(0)" ::: "memory");

    // ---- bf16 correction: 8 chunks of K=32 over KC=256, same schedule ----
    const i8* cA0 = (const i8*)Axo + (size_t)(bm * 256 + r0) * (KC * 2) + q0 * 16;
    const i8* cA1 = (const i8*)Axo + (size_t)(bm * 256 + r1) * (KC * 2) + q1 * 16;
    const i8* cB0 = (const i8*)Bwc + (size_t)(bn * 256 + r0) * (KC * 2) + q0 * 16;
    const i8* cB1 = (const i8*)Bwc + (size_t)(bn * 256 + r1) * (KC * 2) + q1 * 16;
    auto stagec = [&](int c) {
        i8* bs = &ring[c % 5][0][0];
        const int ko = c * 64;
        gload16(cA0 + ko, bs + d0);
        gload16(cA1 + ko, bs + d1);
        gload16(cB0 + ko, bs + 16384 + d0);
        gload16(cB1 + ko, bs + 16384 + d1);
    };
    auto phase_bf = [&](int c) {
        const i8* sA = &ring[c % 5][0][0];
        const i8* sB = sA + 16384;
        bf16x8 af[4][2], bfr[2][2];
#pragma unroll
        for (int mi = 0; mi < 4; ++mi)
#pragma unroll
            for (int ks = 0; ks < 2; ++ks)
                af[mi][ks] = *(const bf16x8*)(sA + offA[mi][ks]);
#pragma unroll
        for (int ni = 0; ni < 2; ++ni)
#pragma unroll
            for (int ks = 0; ks < 2; ++ks)
                bfr[ni][ks] = *(const bf16x8*)(sB + offB[ni][ks]);
        __builtin_amdgcn_s_setprio(1);
#pragma unroll
        for (int ks = 0; ks < 2; ++ks)
#pragma unroll
            for (int mi = 0; mi < 4; ++mi)
#pragma unroll
                for (int ni = 0; ni < 2; ++ni)
                    facc[mi][ni] = __builtin_amdgcn_mfma_f32_32x32x16_bf16(
                        af[mi][ks], bfr[ni][ks], facc[mi][ni], 0, 0, 0);
        __builtin_amdgcn_s_setprio(0);
    };

    stagec(0); stagec(1); stagec(2);
#pragma unroll
    for (int c = 0; c < 5; ++c) {
        stagec(c + 3);
        VMCNT(12); BAR; SCHED0;
        phase_bf(c);
        SCHED0; BAR;
    }
    VMCNT(8); BAR; SCHED0; phase_bf(5); SCHED0; BAR;
    VMCNT(4); BAR; SCHED0; phase_bf(6); SCHED0; BAR;
    VMCNT(0); BAR; SCHED0; phase_bf(7); SCHED0; BAR;

    // ---- epilogue: + bias, store ----
#pragma unroll
    for (int mi = 0; mi < 4; ++mi)
#pragma unroll
        for (int r = 0; r < 16; ++r) {
            const int row = rbase + mi * 32 + (r & 3) + 8 * (r >> 2);
#pragma unroll
            for (int ni = 0; ni < 2; ++ni)
                C[(size_t)row * N + cbase + ni * 32] = facc[mi][ni][r] + bv2[ni];
        }
}

// ---------------------------------------------------------------------------
extern "C" void kernel_launch(void* const* d_in, const int* in_sizes, int n_in,
                              void* d_out, int out_size, void* d_ws, size_t ws_size,
                              hipStream_t stream)
{
    const float* x    = (const float*)d_in[0];
    const float* w    = (const float*)d_in[1];
    const float* bias = (const float*)d_in[2];
    const float* ow   = (const float*)d_in[3];
    const int*   idx  = (const int*)d_in[4];
    const int    n_out = in_sizes[4];
    float* out = (float*)d_out;

    char* ws = (char*)d_ws;
    i8*    xq    = (i8*)ws;                                   // 16 MB
    i8*    wsgn  = (i8*)(ws + (size_t)16 * 1024 * 1024);      // 16 MB
    bf16*  xo    = (bf16*)(ws + (size_t)32 * 1024 * 1024);    // 2 MB
    bf16*  wcorr = (bf16*)(ws + (size_t)34 * 1024 * 1024);    // 2 MB
    float* sx    = (float*)(ws + (size_t)36 * 1024 * 1024);   // 16 KB
    float* scl   = (float*)(ws + (size_t)36 * 1024 * 1024 + 16 * 1024); // 16 KB

    hipLaunchKernelGGL(prep_kernel, dim3(OC_N), dim3(256), 0, stream,
                       w, x, ow, idx, wsgn, xq, xo, wcorr, scl, sx, n_out);
    hipLaunchKernelGGL(gemm_kernel, dim3(256), dim3(512), 0, stream,
                       xq, wsgn, xo, wcorr, sx, scl, bias, out);
}

// Round 5
// 252.562 us; speedup vs baseline: 1.0521x; 1.0093x over previous
//
#include <hip/hip_runtime.h>

typedef __bf16 bf16;
typedef __bf16 bf16x8 __attribute__((ext_vector_type(8)));
typedef float  f32x4  __attribute__((ext_vector_type(4)));
typedef float  f32x16 __attribute__((ext_vector_type(16)));
typedef int    i32x4  __attribute__((ext_vector_type(4)));
typedef int    i32x16 __attribute__((ext_vector_type(16)));
typedef signed char i8;

#define OC_N   4096
#define IC_K   4096
#define TOKENS 4096
#define KC     256   // outlier K padded to 8x32

// ---------------------------------------------------------------------------
// Fused prep, one block per row r (TOKENS == OC_N == 4096).  UNCHANGED.
// ---------------------------------------------------------------------------
__global__ __launch_bounds__(256) void prep_kernel(
    const float* __restrict__ w, const float* __restrict__ x,
    const float* __restrict__ ow, const int* __restrict__ idx,
    i8* __restrict__ wsgn, i8* __restrict__ xq,
    bf16* __restrict__ xo, bf16* __restrict__ wcorr,
    float* __restrict__ scale_arr, float* __restrict__ sx_arr, int n_out)
{
    __shared__ float red[8];
    const int row = blockIdx.x;
    const int t = threadIdx.x;
    const int lane = t & 63, wv = t >> 6;

    const float4* wr = (const float4*)(w + (size_t)row * IC_K);
    const float4* xr = (const float4*)(x + (size_t)row * IC_K);
    float4 v[4], u[4];
#pragma unroll
    for (int i = 0; i < 4; i++) v[i] = wr[i * 256 + t];
#pragma unroll
    for (int i = 0; i < 4; i++) u[i] = xr[i * 256 + t];

    float xg = 0.f, wg = 0.f, og = 0.f;
    if (t < n_out) {
        const int colg = idx[t];
        xg = x[(size_t)row * IC_K + colg];
        wg = w[(size_t)row * IC_K + colg];
        og = ow[(size_t)row * n_out + t];
    }

    float s = 0.f;
#pragma unroll
    for (int i = 0; i < 4; i++)
        s += v[i].x + v[i].y + v[i].z + v[i].w;
    for (int o = 32; o > 0; o >>= 1) s += __shfl_down(s, o, 64);
    if (lane == 0) red[wv] = s;
    __syncthreads();
    const float mean = (red[0] + red[1] + red[2] + red[3]) * (1.f / IC_K);

    float sa = 0.f;
#pragma unroll
    for (int i = 0; i < 4; i++) {
        sa += fabsf(v[i].x - mean) + fabsf(v[i].y - mean) +
              fabsf(v[i].z - mean) + fabsf(v[i].w - mean);
    }
    for (int o = 32; o > 0; o >>= 1) sa += __shfl_down(sa, o, 64);
    if (lane == 0) red[4 + wv] = sa;
    __syncthreads();
    const float scale = (red[4] + red[5] + red[6] + red[7]) * (1.f / IC_K);

    i8* srow = wsgn + (size_t)row * IC_K;
#pragma unroll
    for (int i = 0; i < 4; i++) {
        float c[4] = { v[i].x - mean, v[i].y - mean, v[i].z - mean, v[i].w - mean };
        char4 q;
        q.x = (i8)((c[0] > 0.f) - (c[0] < 0.f));
        q.y = (i8)((c[1] > 0.f) - (c[1] < 0.f));
        q.z = (i8)((c[2] > 0.f) - (c[2] < 0.f));
        q.w = (i8)((c[3] > 0.f) - (c[3] < 0.f));
        *(char4*)(srow + (size_t)(i * 256 + t) * 4) = q;
    }

    float mx = 0.f;
#pragma unroll
    for (int i = 0; i < 4; i++)
        mx = fmaxf(mx, fmaxf(fmaxf(fabsf(u[i].x), fabsf(u[i].y)),
                             fmaxf(fabsf(u[i].z), fabsf(u[i].w))));
    for (int o = 32; o > 0; o >>= 1) mx = fmaxf(mx, __shfl_down(mx, o, 64));
    if (lane == 0) red[wv] = mx;
    __syncthreads();
    const float maxv = fmaxf(fmaxf(red[0], red[1]), fmaxf(red[2], red[3]));
    const float inv = maxv > 0.f ? 127.f / maxv : 0.f;
    const float sxv = maxv > 0.f ? maxv * (1.f / 127.f) : 1.f;

    i8* xrow = xq + (size_t)row * IC_K;
#pragma unroll
    for (int i = 0; i < 4; i++) {
        char4 q;
        q.x = (i8)(int)rintf(u[i].x * inv);
        q.y = (i8)(int)rintf(u[i].y * inv);
        q.z = (i8)(int)rintf(u[i].z * inv);
        q.w = (i8)(int)rintf(u[i].w * inv);
        *(char4*)(xrow + (size_t)(i * 256 + t) * 4) = q;
    }
    if (t == 0) { scale_arr[row] = scale; sx_arr[row] = sxv; }

    if (t < n_out) {
        xo[(size_t)row * KC + t] = (bf16)xg;
        const float wc_ = wg - mean;
        const float sg = (wc_ > 0.f) ? 1.f : ((wc_ < 0.f) ? -1.f : 0.f);
        wcorr[(size_t)row * KC + t] = (bf16)(og - scale * sg);
    } else if (t < KC) {
        xo[(size_t)row * KC + t] = (bf16)0.f;
        wcorr[(size_t)row * KC + t] = (bf16)0.f;
    }
}

// ---------------------------------------------------------------------------
// GEMM v4: 256x256 tile, 8 waves (2Mx4N), counted-vmcnt ring, depth 5.
// v3 measured: gemm 90.8us, FETCH 55.5MB (4x8 XCD tiling confirmed),
// MfmaUtil 36%, conflicts 7.08M (=+4cy/ds_read, gload-write port tax).
// Phase cost 2850cy vs 1170cy MFMA floor -> ~1700cy/phase barrier-lockstep
// slack with TWO block barriers per phase at 2 waves/SIMD.
// Change v3 -> v4: ONE barrier per phase.  New iteration order:
//   VMCNT(12); BAR; stage(c+4); ds_reads(c); MFMAs(c)
// The iter-start barrier proves all waves consumed phase c-1 (their MFMAs
// lgkm-waited the ds_reads before reaching it), so the trailing WAR barrier
// is redundant once stage is issued AFTER the wait.
// Race audit: during iter c, in-flight writes target slots (c+1..c+4)%5,
// reads target c%5 -> disjoint.  stage(c+5) (iter c+1) touches slot c%5
// only after the iter-c+1 barrier, by which all phase-c reads completed.
// RAW: VMCNT(12);BAR -> every wave's chunk-c loads are in LDS before any
// wave reads them.  i8->bf16 boundary keeps an explicit vmcnt(0)+BAR
// before stagec(0..2); first bf16 iter's barrier precedes stagec(3) which
// reuses slot 3 (last read in phase_i8(63)).
// Ledger: prologue 4 chunks (16 loads); steady wait 12; tail 12/8/4/0.
// bf16 loop: 3-chunk prologue (12 loads), steady wait 8, tail 8/4/0.
// ---------------------------------------------------------------------------
__device__ __forceinline__ void gload16(const void* g, void* l)
{
    __builtin_amdgcn_global_load_lds(
        (const __attribute__((address_space(1))) void*)g,
        (__attribute__((address_space(3))) void*)l, 16, 0, 0);
}

#define VMCNT(n) asm volatile("s_waitcnt vmcnt(" #n ")" ::: "memory")
#define SCHED0   __builtin_amdgcn_sched_barrier(0)
#define BAR      __builtin_amdgcn_s_barrier()

__global__ __launch_bounds__(512, 2) void gemm_kernel(
    const i8* __restrict__ A, const i8* __restrict__ B,
    const bf16* __restrict__ Axo, const bf16* __restrict__ Bwc,
    const float* __restrict__ sx, const float* __restrict__ scale,
    const float* __restrict__ bias, float* __restrict__ C)
{
    constexpr int K = IC_K, N = OC_N;
    __shared__ __align__(16) i8 ring[5][2][16384];   // 160 KB (full pool)

    const int tid  = threadIdx.x;
    const int lane = tid & 63;
    const int wave = tid >> 6;
    const int wm = wave >> 2, wn = wave & 3;          // 2 (M) x 4 (N) waves
    const int m32 = lane & 31, kg = lane >> 5;

    // XCD-aware 4x8 rectangle per XCD (bijective; 256 blocks, 8 XCDs)
    const int bid = blockIdx.x;
    const int xcd = bid & 7, tix = bid >> 3;          // 32 tiles per XCD
    const int bm = (xcd >> 1) * 4 + (tix & 3);        // 16 values
    const int bn = (xcd & 1) * 8 + (tix >> 2);        // 16 values

    // ---- staging map: LDS quad Q = tid (+512) -> (row, swizzled qk) ----
    const int Q0 = tid, Q1 = 512 + tid;
    const int r0 = Q0 >> 2, r1 = Q1 >> 2;             // rows 0..127 / 128..255
    const int q0 = (Q0 & 3) ^ ((r0 >> 1) & 3);
    const int q1 = (Q1 & 3) ^ ((r1 >> 1) & 3);
    const int d0 = Q0 * 16, d1 = Q1 * 16;

    const i8* gA0 = A + (size_t)(bm * 256 + r0) * K + q0 * 16;
    const i8* gA1 = A + (size_t)(bm * 256 + r1) * K + q1 * 16;
    const i8* gB0 = B + (size_t)(bn * 256 + r0) * K + q0 * 16;
    const i8* gB1 = B + (size_t)(bn * 256 + r1) * K + q1 * 16;

    auto stage = [&](int c) {
        i8* bs = &ring[c % 5][0][0];
        const int ko = c * 64;
        gload16(gA0 + ko, bs + d0);
        gload16(gA1 + ko, bs + d1);
        gload16(gB0 + ko, bs + 16384 + d0);
        gload16(gB1 + ko, bs + 16384 + d1);
    };

    // ---- per-lane ds_read byte offsets (shared by i8 and bf16 loops) ----
    int offA[4][2], offB[2][2];
#pragma unroll
    for (int mi = 0; mi < 4; ++mi) {
        const int r = wm * 128 + mi * 32 + m32;
#pragma unroll
        for (int ks = 0; ks < 2; ++ks)
            offA[mi][ks] = r * 64 + ((ks * 2 + kg) ^ ((r >> 1) & 3)) * 16;
    }
#pragma unroll
    for (int ni = 0; ni < 2; ++ni) {
        const int r = wn * 64 + ni * 32 + m32;
#pragma unroll
        for (int ks = 0; ks < 2; ++ks)
            offB[ni][ks] = r * 64 + ((ks * 2 + kg) ^ ((r >> 1) & 3)) * 16;
    }

    i32x16 acc[4][2] = {};

    auto phase_i8 = [&](int c) {
        const i8* sA = &ring[c % 5][0][0];
        const i8* sB = sA + 16384;
        i32x4 af[4][2], bfr[2][2];
#pragma unroll
        for (int mi = 0; mi < 4; ++mi)
#pragma unroll
            for (int ks = 0; ks < 2; ++ks)
                af[mi][ks] = *(const i32x4*)(sA + offA[mi][ks]);
#pragma unroll
        for (int ni = 0; ni < 2; ++ni)
#pragma unroll
            for (int ks = 0; ks < 2; ++ks)
                bfr[ni][ks] = *(const i32x4*)(sB + offB[ni][ks]);
        __builtin_amdgcn_s_setprio(1);
#pragma unroll
        for (int ks = 0; ks < 2; ++ks)
#pragma unroll
            for (int mi = 0; mi < 4; ++mi)
#pragma unroll
                for (int ni = 0; ni < 2; ++ni)
                    acc[mi][ni] = __builtin_amdgcn_mfma_i32_32x32x32_i8(
                        af[mi][ks], bfr[ni][ks], acc[mi][ni], 0, 0, 0);
        __builtin_amdgcn_s_setprio(0);
    };

    // ---- main i8 loop: 64 chunks, depth 5, ONE barrier per phase ----
    stage(0); stage(1); stage(2); stage(3);
#pragma unroll 5
    for (int c = 0; c < 60; ++c) {
        VMCNT(12); BAR; SCHED0;
        stage(c + 4);
        phase_i8(c);
    }
    VMCNT(12); BAR; SCHED0; phase_i8(60);
    VMCNT(8);  BAR; SCHED0; phase_i8(61);
    VMCNT(4);  BAR; SCHED0; phase_i8(62);
    VMCNT(0);  BAR; SCHED0; phase_i8(63);

    // ---- i32 -> f32 scaling (32x32 C layout: row=(r&3)+8*(r>>2)+4*kg) ----
    const int rbase = bm * 256 + wm * 128 + 4 * kg;
    const int cbase = bn * 256 + wn * 64 + m32;
    float scl2[2], bv2[2];
#pragma unroll
    for (int ni = 0; ni < 2; ++ni) {
        scl2[ni] = scale[cbase + ni * 32];
        bv2[ni]  = bias[cbase + ni * 32];
    }
    f32x16 facc[4][2];
#pragma unroll
    for (int mi = 0; mi < 4; ++mi)
#pragma unroll
        for (int r = 0; r < 16; ++r) {
            const float sxv = sx[rbase + mi * 32 + (r & 3) + 8 * (r >> 2)];
#pragma unroll
            for (int ni = 0; ni < 2; ++ni)
                facc[mi][ni][r] = (float)acc[mi][ni][r] * sxv * scl2[ni];
        }
    // drain sx/scale/bias loads (exact vmcnt counts for corr loop) and
    // barrier: all waves' i8-phase LDS reads are done before slot reuse.
    asm volatile("s_waitcnt vmcnt(0)" ::: "memory");
    BAR;

    // ---- bf16 correction: 8 chunks of K=32 over KC=256, same schedule ----
    const i8* cA0 = (const i8*)Axo + (size_t)(bm * 256 + r0) * (KC * 2) + q0 * 16;
    const i8* cA1 = (const i8*)Axo + (size_t)(bm * 256 + r1) * (KC * 2) + q1 * 16;
    const i8* cB0 = (const i8*)Bwc + (size_t)(bn * 256 + r0) * (KC * 2) + q0 * 16;
    const i8* cB1 = (const i8*)Bwc + (size_t)(bn * 256 + r1) * (KC * 2) + q1 * 16;
    auto stagec = [&](int c) {
        i8* bs = &ring[c % 5][0][0];
        const int ko = c * 64;
        gload16(cA0 + ko, bs + d0);
        gload16(cA1 + ko, bs + d1);
        gload16(cB0 + ko, bs + 16384 + d0);
        gload16(cB1 + ko, bs + 16384 + d1);
    };
    auto phase_bf = [&](int c) {
        const i8* sA = &ring[c % 5][0][0];
        const i8* sB = sA + 16384;
        bf16x8 af[4][2], bfr[2][2];
#pragma unroll
        for (int mi = 0; mi < 4; ++mi)
#pragma unroll
            for (int ks = 0; ks < 2; ++ks)
                af[mi][ks] = *(const bf16x8*)(sA + offA[mi][ks]);
#pragma unroll
        for (int ni = 0; ni < 2; ++ni)
#pragma unroll
            for (int ks = 0; ks < 2; ++ks)
                bfr[ni][ks] = *(const bf16x8*)(sB + offB[ni][ks]);
        __builtin_amdgcn_s_setprio(1);
#pragma unroll
        for (int ks = 0; ks < 2; ++ks)
#pragma unroll
            for (int mi = 0; mi < 4; ++mi)
#pragma unroll
                for (int ni = 0; ni < 2; ++ni)
                    facc[mi][ni] = __builtin_amdgcn_mfma_f32_32x32x16_bf16(
                        af[mi][ks], bfr[ni][ks], facc[mi][ni], 0, 0, 0);
        __builtin_amdgcn_s_setprio(0);
    };

    stagec(0); stagec(1); stagec(2);
#pragma unroll
    for (int c = 0; c < 5; ++c) {
        VMCNT(8); BAR; SCHED0;
        stagec(c + 3);
        phase_bf(c);
    }
    VMCNT(8); BAR; SCHED0; phase_bf(5);
    VMCNT(4); BAR; SCHED0; phase_bf(6);
    VMCNT(0); BAR; SCHED0; phase_bf(7);

    // ---- epilogue: + bias, store ----
#pragma unroll
    for (int mi = 0; mi < 4; ++mi)
#pragma unroll
        for (int r = 0; r < 16; ++r) {
            const int row = rbase + mi * 32 + (r & 3) + 8 * (r >> 2);
#pragma unroll
            for (int ni = 0; ni < 2; ++ni)
                C[(size_t)row * N + cbase + ni * 32] = facc[mi][ni][r] + bv2[ni];
        }
}

// ---------------------------------------------------------------------------
extern "C" void kernel_launch(void* const* d_in, const int* in_sizes, int n_in,
                              void* d_out, int out_size, void* d_ws, size_t ws_size,
                              hipStream_t stream)
{
    const float* x    = (const float*)d_in[0];
    const float* w    = (const float*)d_in[1];
    const float* bias = (const float*)d_in[2];
    const float* ow   = (const float*)d_in[3];
    const int*   idx  = (const int*)d_in[4];
    const int    n_out = in_sizes[4];
    float* out = (float*)d_out;

    char* ws = (char*)d_ws;
    i8*    xq    = (i8*)ws;                                   // 16 MB
    i8*    wsgn  = (i8*)(ws + (size_t)16 * 1024 * 1024);      // 16 MB
    bf16*  xo    = (bf16*)(ws + (size_t)32 * 1024 * 1024);    // 2 MB
    bf16*  wcorr = (bf16*)(ws + (size_t)34 * 1024 * 1024);    // 2 MB
    float* sx    = (float*)(ws + (size_t)36 * 1024 * 1024);   // 16 KB
    float* scl   = (float*)(ws + (size_t)36 * 1024 * 1024 + 16 * 1024); // 16 KB

    hipLaunchKernelGGL(prep_kernel, dim3(OC_N), dim3(256), 0, stream,
                       w, x, ow, idx, wsgn, xq, xo, wcorr, scl, sx, n_out);
    hipLaunchKernelGGL(gemm_kernel, dim3(256), dim3(512), 0, stream,
                       xq, wsgn, xo, wcorr, sx, scl, bias, out);
}